// Round 1
// baseline (9733.421 us; speedup 1.0000x reference)
//
#include <hip/hip_runtime.h>

// QINCo fp32 implementation.
// Shapes: D=128, M=8, K=256, L=2, H=256, BS=1024. All inputs fp32.
// Out layout (floats): xhat[1024*128] | codes[1024*8] (as float) | side[8][1024*128]

#define OUT_CODES 131072
#define OUT_SIDE  139264

// ws float offsets
#define WS_XHAT  0          // [1024][128]
#define WS_RB    131072     // [1024][128]  r = x - xhat
#define WS_Y     262144     // [1024][128]  y = xhat @ Wx^T
#define WS_ZC    393216     // [256][128]   zc = cb + cb@Wz^T + bc
#define WS_BESTD 425984     // [1024][4]
#define WS_BESTI 430080     // [1024][4] (int)
#define WS_BESTZ 434176     // [1024][4][128]

// Per-row float4 rotation so stride-8 row groups hit distinct LDS banks.
__device__ __forceinline__ int rotaddr(int r, int d) {
  return (r << 7) + ((d + ((r & 7) << 2)) & 127);
}

// ---------------- step 0: nearest codebook0 row ----------------
__global__ __launch_bounds__(256) void k_step0(const float* __restrict__ x,
    const float* __restrict__ cb0, float* __restrict__ ws, float* __restrict__ out)
{
  __shared__ float xs[128];
  __shared__ float redv[4];
  __shared__ int   redi[4];
  __shared__ int   kwin;
  int tx = threadIdx.x, b = blockIdx.x;
  if (tx < 128) xs[tx] = x[b * 128 + tx];
  __syncthreads();
  const float* c = cb0 + tx * 128;   // k = tx
  float s = 0.f;
  for (int d = 0; d < 128; d += 4) {
    float4 cv = *(const float4*)(c + d);
    float4 xv = *(const float4*)(xs + d);
    float a0 = xv.x - cv.x, a1 = xv.y - cv.y, a2 = xv.z - cv.z, a3 = xv.w - cv.w;
    s += a0 * a0 + a1 * a1 + a2 * a2 + a3 * a3;
  }
  float v = s; int idx = tx;
  for (int off = 32; off; off >>= 1) {
    float v2 = __shfl_xor(v, off);
    int   i2 = __shfl_xor(idx, off);
    if (v2 < v || (v2 == v && i2 < idx)) { v = v2; idx = i2; }
  }
  if ((tx & 63) == 0) { redv[tx >> 6] = v; redi[tx >> 6] = idx; }
  __syncthreads();
  if (tx == 0) {
    float bv = redv[0]; int bi = redi[0];
    for (int w = 1; w < 4; w++)
      if (redv[w] < bv || (redv[w] == bv && redi[w] < bi)) { bv = redv[w]; bi = redi[w]; }
    kwin = bi;
    out[OUT_CODES + b * 8] = (float)bi;
  }
  __syncthreads();
  int k = kwin;
  if (tx < 128) {
    float xh = cb0[k * 128 + tx];
    ws[WS_XHAT + b * 128 + tx] = xh;
    ws[WS_RB   + b * 128 + tx] = xs[tx] - xh;
    out[OUT_SIDE + b * 128 + tx] = xh;   // side[0]
  }
}

// ---------------- per-step prep: zc and y ----------------
__global__ __launch_bounds__(128) void k_prep(const float* __restrict__ cb,
    const float* __restrict__ Wc, const float* __restrict__ bcm, float* __restrict__ ws)
{
  __shared__ float row[128];
  int tx = threadIdx.x, blk = blockIdx.x;
  if (blk < 256) {          // zc[k][i] = cb[k][i] + sum_d cb[k][d]*Wc[i][d] + bc[i]
    row[tx] = cb[blk * 128 + tx];
    __syncthreads();
    const float* wrow = Wc + tx * 256;
    float s = 0.f;
    for (int d = 0; d < 128; d += 4) {
      float4 wv = *(const float4*)(wrow + d);
      float4 zv = *(const float4*)(row + d);
      s += wv.x * zv.x + wv.y * zv.y + wv.z * zv.z + wv.w * zv.w;
    }
    ws[WS_ZC + blk * 128 + tx] = row[tx] + s + bcm[tx];
  } else {                  // y[b][i] = sum_d xhat[b][d]*Wc[i][128+d]
    int b = blk - 256;
    row[tx] = ws[WS_XHAT + b * 128 + tx];
    __syncthreads();
    const float* wrow = Wc + tx * 256 + 128;
    float s = 0.f;
    for (int d = 0; d < 128; d += 4) {
      float4 wv = *(const float4*)(wrow + d);
      float4 zv = *(const float4*)(row + d);
      s += wv.x * zv.x + wv.y * zv.y + wv.z * zv.z + wv.w * zv.w;
    }
    ws[WS_Y + b * 128 + tx] = s;
  }
}

// ---------------- main step kernel: 64 candidates of one b ----------------
// 128 threads; LDS: Z[64][128] + Hs[64][128] = 64KB exactly -> 2 WGs/CU.
// Micro-tiling: rows r = 8*i + rg (rg=tx&7), GEMM1 cols {4cg, 64+4cg} (cg=tx>>3).
__global__ __launch_bounds__(128, 1) void k_step(const float* __restrict__ W1g,
    const float* __restrict__ W2g, float* __restrict__ ws, int m)
{
  __shared__ float Z[8192];
  __shared__ float Hs[8192];
  int tx = threadIdx.x;
  int b = blockIdx.x >> 2, t = blockIdx.x & 3, k0 = t << 6;
  int rg = tx & 7, cg = tx >> 3;   // cg in 0..15

  // init Z = zc[k0+r] + y[b]  (rotated store)
  {
    const float* zc = ws + WS_ZC + k0 * 128;
    const float* y  = ws + WS_Y + b * 128;
    for (int i = tx; i < 2048; i += 128) {
      int r = i >> 5, dq = (i & 31) << 2;
      float4 zv = *(const float4*)(zc + r * 128 + dq);
      float4 yv = *(const float4*)(y + dq);
      zv.x += yv.x; zv.y += yv.y; zv.z += yv.z; zv.w += yv.w;
      *(float4*)(Z + rotaddr(r, dq)) = zv;
    }
  }
  __syncthreads();

  float acc2[8][8];
  for (int l = 0; l < 2; l++) {
    const float* w1 = W1g + (size_t)(m * 2 + l) * (256 * 128);
    const float* w2 = W2g + (size_t)(m * 2 + l) * (128 * 256);
#pragma unroll
    for (int i = 0; i < 8; i++)
#pragma unroll
      for (int q = 0; q < 8; q++) acc2[i][q] = 0.f;

    for (int pass = 0; pass < 2; pass++) {
      const int jbase = pass << 7;
      // ---- GEMM1: Hs[r][jl] = relu(sum_d Z[r][d] * W1[jbase+jl][d]) ----
      {
        float a1[8][8];
#pragma unroll
        for (int i = 0; i < 8; i++)
#pragma unroll
          for (int q = 0; q < 8; q++) a1[i][q] = 0.f;
        const float* w1a = w1 + (jbase + (cg << 2)) * 128;
        const float* w1b = w1a + 64 * 128;
        for (int d = 0; d < 128; d += 4) {
          int col = (d + (rg << 2)) & 127;
          float4 zv[8];
#pragma unroll
          for (int i = 0; i < 8; i++)
            zv[i] = *(const float4*)(Z + (((i << 3) + rg) << 7) + col);
#pragma unroll
          for (int jj = 0; jj < 4; jj++) {
            float4 wa = *(const float4*)(w1a + jj * 128 + d);
            float4 wb = *(const float4*)(w1b + jj * 128 + d);
#pragma unroll
            for (int i = 0; i < 8; i++) {
              a1[i][jj]     += zv[i].x * wa.x + zv[i].y * wa.y + zv[i].z * wa.z + zv[i].w * wa.w;
              a1[i][4 + jj] += zv[i].x * wb.x + zv[i].y * wb.y + zv[i].z * wb.z + zv[i].w * wb.w;
            }
          }
        }
#pragma unroll
        for (int i = 0; i < 8; i++) {
          int r = (i << 3) + rg;
          float4 ha, hb;
          ha.x = fmaxf(a1[i][0], 0.f); ha.y = fmaxf(a1[i][1], 0.f);
          ha.z = fmaxf(a1[i][2], 0.f); ha.w = fmaxf(a1[i][3], 0.f);
          hb.x = fmaxf(a1[i][4], 0.f); hb.y = fmaxf(a1[i][5], 0.f);
          hb.z = fmaxf(a1[i][6], 0.f); hb.w = fmaxf(a1[i][7], 0.f);
          *(float4*)(Hs + rotaddr(r, cg << 2)) = ha;
          *(float4*)(Hs + rotaddr(r, 64 + (cg << 2))) = hb;
        }
      }
      __syncthreads();
      // ---- GEMM2 partial: acc2 += Hs @ W2[:, jbase:jbase+128]^T ----
      {
        const float* w2a = w2 + (cg << 2) * 256 + jbase;
        const float* w2b = w2a + 64 * 256;
        for (int j = 0; j < 128; j += 4) {
          int col = (j + (rg << 2)) & 127;
          float4 hv[8];
#pragma unroll
          for (int i = 0; i < 8; i++)
            hv[i] = *(const float4*)(Hs + (((i << 3) + rg) << 7) + col);
#pragma unroll
          for (int q = 0; q < 4; q++) {
            float4 wa = *(const float4*)(w2a + q * 256 + j);
            float4 wb = *(const float4*)(w2b + q * 256 + j);
#pragma unroll
            for (int i = 0; i < 8; i++) {
              acc2[i][q]     += hv[i].x * wa.x + hv[i].y * wa.y + hv[i].z * wa.z + hv[i].w * wa.w;
              acc2[i][4 + q] += hv[i].x * wb.x + hv[i].y * wb.y + hv[i].z * wb.z + hv[i].w * wb.w;
            }
          }
        }
      }
      __syncthreads();
    }
    // Z += acc2  (thread-exclusive slots)
#pragma unroll
    for (int i = 0; i < 8; i++) {
      int r = (i << 3) + rg;
      float4* pa = (float4*)(Z + rotaddr(r, cg << 2));
      float4* pb = (float4*)(Z + rotaddr(r, 64 + (cg << 2)));
      float4 za = *pa, zb = *pb;
      za.x += acc2[i][0]; za.y += acc2[i][1]; za.z += acc2[i][2]; za.w += acc2[i][3];
      zb.x += acc2[i][4]; zb.y += acc2[i][5]; zb.z += acc2[i][6]; zb.w += acc2[i][7];
      *pa = za; *pb = zb;
    }
    __syncthreads();
  }

  // ---- dist = ||rb - z||^2, argmin over 64 rows ----
  float* pd  = Hs;            // Hs free now
  int* rwin  = (int*)(Hs + 64);
  {
    const float* rb = ws + WS_RB + b * 128;
    int r = tx >> 1, hf = tx & 1;
    float s = 0.f;
    int dbase = hf << 6;
    for (int d = 0; d < 64; d += 4) {
      float4 zv = *(const float4*)(Z + rotaddr(r, dbase + d));
      float4 rv = *(const float4*)(rb + dbase + d);
      float a0 = rv.x - zv.x, a1 = rv.y - zv.y, a2 = rv.z - zv.z, a3 = rv.w - zv.w;
      s += a0 * a0 + a1 * a1 + a2 * a2 + a3 * a3;
    }
    s += __shfl_xor(s, 1);    // commutative add: both lanes bit-identical
    if (hf == 0) pd[r] = s;
  }
  __syncthreads();
  if (tx < 64) {
    float v = pd[tx]; int idx = tx;
#pragma unroll
    for (int off = 32; off; off >>= 1) {
      float v2 = __shfl_xor(v, off);
      int   i2 = __shfl_xor(idx, off);
      if (v2 < v || (v2 == v && i2 < idx)) { v = v2; idx = i2; }
    }
    if (tx == 0) {
      ws[WS_BESTD + (b << 2) + t] = v;
      ((int*)ws)[WS_BESTI + (b << 2) + t] = k0 + idx;
      rwin[0] = idx;
    }
  }
  __syncthreads();
  if (tx < 32) {
    int rw = rwin[0];
    *(float4*)(ws + WS_BESTZ + (((b << 2) + t) << 7) + (tx << 2)) =
        *(const float4*)(Z + rotaddr(rw, tx << 2));
  }
}

// ---------------- per-step update: pick tile winner, advance xhat ----------------
__global__ __launch_bounds__(128) void k_update(const float* __restrict__ x,
    float* __restrict__ ws, float* __restrict__ out, int m, int last)
{
  __shared__ int tsel;
  int tx = threadIdx.x, b = blockIdx.x;
  if (tx == 0) {
    float bv = ws[WS_BESTD + (b << 2)]; int bt = 0;
    for (int q = 1; q < 4; q++) {
      float v = ws[WS_BESTD + (b << 2) + q];
      if (v < bv) { bv = v; bt = q; }     // strict <: ties -> lowest k (tile order)
    }
    tsel = bt;
    int k = ((const int*)ws)[WS_BESTI + (b << 2) + bt];
    out[OUT_CODES + b * 8 + (m + 1)] = (float)k;
  }
  __syncthreads();
  int bt = tsel;
  float z  = ws[WS_BESTZ + (((b << 2) + bt) << 7) + tx];
  float xh = ws[WS_XHAT + b * 128 + tx] + z;
  ws[WS_XHAT + b * 128 + tx] = xh;
  ws[WS_RB   + b * 128 + tx] = x[b * 128 + tx] - xh;
  out[OUT_SIDE + (m + 1) * 131072 + b * 128 + tx] = xh;
  if (last) out[b * 128 + tx] = xh;       // final xhat == side[7]
}

extern "C" void kernel_launch(void* const* d_in, const int* in_sizes, int n_in,
                              void* d_out, int out_size, void* d_ws, size_t ws_size,
                              hipStream_t stream)
{
  const float* x   = (const float*)d_in[0];
  const float* cb0 = (const float*)d_in[1];
  const float* cbs = (const float*)d_in[2];
  const float* Wc  = (const float*)d_in[3];
  const float* bc  = (const float*)d_in[4];
  const float* W1  = (const float*)d_in[5];
  const float* W2  = (const float*)d_in[6];
  float* out = (float*)d_out;
  float* ws  = (float*)d_ws;

  k_step0<<<1024, 256, 0, stream>>>(x, cb0, ws, out);
  for (int m = 0; m < 7; m++) {
    k_prep<<<1280, 128, 0, stream>>>(cbs + m * 256 * 128, Wc + m * 128 * 256,
                                     bc + m * 128, ws);
    k_step<<<4096, 128, 0, stream>>>(W1, W2, ws, m);
    k_update<<<1024, 128, 0, stream>>>(x, ws, out, m, (m == 6) ? 1 : 0);
  }
}

// Round 3
// 8045.309 us; speedup vs baseline: 1.2098x; 1.2098x over previous
//
#include <hip/hip_runtime.h>

// QINCo fp32 implementation, round 3: round-2 occupancy structure with the
// rotation bug fixed (weights indexed by LOGICAL d/h; LDS reads use the
// physical rotated column).
// Shapes: D=128, M=8, K=256, L=2, H=256, BS=1024. All inputs fp32.
// Out layout (floats): xhat[1024*128] | codes[1024*8] (as float) | side[8][1024*128]

#define OUT_CODES 131072
#define OUT_SIDE  139264

// ws float offsets
#define WS_XHAT  0          // [1024][128]
#define WS_RB    131072     // [1024][128]  r = x - xhat
#define WS_Y     262144     // [1024][128]  y = xhat @ Wx^T
#define WS_ZC    393216     // [256][128]   zc = cb + cb@Wz^T + bc
#define WS_BESTD 425984     // [1024][4]
#define WS_BESTI 430080     // [1024][4] (int)
#define WS_BESTZ 434176     // [1024][4][128]

// Per-row float4 rotation so row groups hit distinct LDS banks on the hot reads.
// Logical element d of row r lives at physical column (d + (r&7)*4) & 127.
__device__ __forceinline__ int rotZ(int r, int d) {
  return (r << 7) + ((d + ((r & 7) << 2)) & 127);
}
__device__ __forceinline__ int rotH(int r, int h) {
  return (r << 6) + ((h + ((r & 7) << 2)) & 63);
}

// ---------------- step 0: nearest codebook0 row ----------------
__global__ __launch_bounds__(256) void k_step0(const float* __restrict__ x,
    const float* __restrict__ cb0, float* __restrict__ ws, float* __restrict__ out)
{
  __shared__ float xs[128];
  __shared__ float redv[4];
  __shared__ int   redi[4];
  __shared__ int   kwin;
  int tx = threadIdx.x, b = blockIdx.x;
  if (tx < 128) xs[tx] = x[b * 128 + tx];
  __syncthreads();
  const float* c = cb0 + tx * 128;   // k = tx
  float s = 0.f;
  for (int d = 0; d < 128; d += 4) {
    float4 cv = *(const float4*)(c + d);
    float4 xv = *(const float4*)(xs + d);
    float a0 = xv.x - cv.x, a1 = xv.y - cv.y, a2 = xv.z - cv.z, a3 = xv.w - cv.w;
    s += a0 * a0 + a1 * a1 + a2 * a2 + a3 * a3;
  }
  float v = s; int idx = tx;
  for (int off = 32; off; off >>= 1) {
    float v2 = __shfl_xor(v, off);
    int   i2 = __shfl_xor(idx, off);
    if (v2 < v || (v2 == v && i2 < idx)) { v = v2; idx = i2; }
  }
  if ((tx & 63) == 0) { redv[tx >> 6] = v; redi[tx >> 6] = idx; }
  __syncthreads();
  if (tx == 0) {
    float bv = redv[0]; int bi = redi[0];
    for (int w = 1; w < 4; w++)
      if (redv[w] < bv || (redv[w] == bv && redi[w] < bi)) { bv = redv[w]; bi = redi[w]; }
    kwin = bi;
    out[OUT_CODES + b * 8] = (float)bi;
  }
  __syncthreads();
  int k = kwin;
  if (tx < 128) {
    float xh = cb0[k * 128 + tx];
    ws[WS_XHAT + b * 128 + tx] = xh;
    ws[WS_RB   + b * 128 + tx] = xs[tx] - xh;
    out[OUT_SIDE + b * 128 + tx] = xh;   // side[0]
  }
}

// ---------------- per-step prep: zc and y ----------------
__global__ __launch_bounds__(128) void k_prep(const float* __restrict__ cb,
    const float* __restrict__ Wc, const float* __restrict__ bcm, float* __restrict__ ws)
{
  __shared__ float row[128];
  int tx = threadIdx.x, blk = blockIdx.x;
  if (blk < 256) {          // zc[k][i] = cb[k][i] + sum_d cb[k][d]*Wc[i][d] + bc[i]
    row[tx] = cb[blk * 128 + tx];
    __syncthreads();
    const float* wrow = Wc + tx * 256;
    float s = 0.f;
    for (int d = 0; d < 128; d += 4) {
      float4 wv = *(const float4*)(wrow + d);
      float4 zv = *(const float4*)(row + d);
      s += wv.x * zv.x + wv.y * zv.y + wv.z * zv.z + wv.w * zv.w;
    }
    ws[WS_ZC + blk * 128 + tx] = row[tx] + s + bcm[tx];
  } else {                  // y[b][i] = sum_d xhat[b][d]*Wc[i][128+d]
    int b = blk - 256;
    row[tx] = ws[WS_XHAT + b * 128 + tx];
    __syncthreads();
    const float* wrow = Wc + tx * 256 + 128;
    float s = 0.f;
    for (int d = 0; d < 128; d += 4) {
      float4 wv = *(const float4*)(wrow + d);
      float4 zv = *(const float4*)(row + d);
      s += wv.x * zv.x + wv.y * zv.y + wv.z * zv.z + wv.w * zv.w;
    }
    ws[WS_Y + b * 128 + tx] = s;
  }
}

// ---------------- main step kernel: 64 candidates of one b ----------------
// 256 threads; LDS: Z[64][128] (32KB) + Hb[64][64] (16KB) = 48KB -> 3 WGs/CU,
// 12 waves/CU (37.5% occupancy). H=256 processed in 4 blocks of 64.
// Thread grid: rg = tx&15 -> rows r = 16*i+rg (i=0..3); cg = tx>>4 (0..15).
__global__ __launch_bounds__(256, 3) void k_step(const float* __restrict__ W1g,
    const float* __restrict__ W2g, float* __restrict__ ws, int m)
{
  __shared__ float Z[8192];
  __shared__ float Hb[4096];
  int tx = threadIdx.x;
  int b = blockIdx.x >> 2, t = blockIdx.x & 3, k0 = t << 6;
  int rg = tx & 15, cg = tx >> 4;
  int rot = (rg & 7) << 2;          // rotation of all rows r with r&7 == rg&7

  // init Z = zc[k0+r] + y[b]  (rotated store)
  {
    const float* zc = ws + WS_ZC + k0 * 128;
    const float* y  = ws + WS_Y + b * 128;
    for (int i = tx; i < 2048; i += 256) {
      int r = i >> 5, dq = (i & 31) << 2;
      float4 zv = *(const float4*)(zc + r * 128 + dq);
      float4 yv = *(const float4*)(y + dq);
      zv.x += yv.x; zv.y += yv.y; zv.z += yv.z; zv.w += yv.w;
      *(float4*)(Z + rotZ(r, dq)) = zv;
    }
  }
  __syncthreads();

  for (int l = 0; l < 2; l++) {
    const float* w1 = W1g + (size_t)(m * 2 + l) * (256 * 128);
    const float* w2 = W2g + (size_t)(m * 2 + l) * (128 * 256);
    float acc2[4][8];
#pragma unroll
    for (int i = 0; i < 4; i++)
#pragma unroll
      for (int q = 0; q < 8; q++) acc2[i][q] = 0.f;

    for (int hb = 0; hb < 4; hb++) {
      // ---- GEMM1: Hb[r][jl] = relu(sum_d Z[r][d] * W1[hb*64+jl][d]) ----
      {
        float a1[4][4];
#pragma unroll
        for (int i = 0; i < 4; i++)
#pragma unroll
          for (int q = 0; q < 4; q++) a1[i][q] = 0.f;
        const float* w1a = w1 + (hb * 64 + (cg << 2)) * 128;
        for (int d = 0; d < 128; d += 4) {
          int col = (d + rot) & 127;        // physical col of LOGICAL element d
          float4 zv[4];
#pragma unroll
          for (int i = 0; i < 4; i++)
            zv[i] = *(const float4*)(Z + (((i << 4) + rg) << 7) + col);
#pragma unroll
          for (int jj = 0; jj < 4; jj++) {
            float4 wa = *(const float4*)(w1a + jj * 128 + d);   // logical d
#pragma unroll
            for (int i = 0; i < 4; i++)
              a1[i][jj] += zv[i].x * wa.x + zv[i].y * wa.y + zv[i].z * wa.z + zv[i].w * wa.w;
          }
        }
#pragma unroll
        for (int i = 0; i < 4; i++) {
          int r = (i << 4) + rg;
          float4 hv;
          hv.x = fmaxf(a1[i][0], 0.f); hv.y = fmaxf(a1[i][1], 0.f);
          hv.z = fmaxf(a1[i][2], 0.f); hv.w = fmaxf(a1[i][3], 0.f);
          *(float4*)(Hb + rotH(r, cg << 2)) = hv;
        }
      }
      __syncthreads();
      // ---- GEMM2 partial: acc2 += Hb @ W2[:, hb*64 : hb*64+64]^T ----
      {
        const float* w2a = w2 + (cg << 2) * 256 + hb * 64;
        const float* w2b = w2a + 64 * 256;
        for (int h = 0; h < 64; h += 4) {
          int colh = (h + rot) & 63;        // physical col of LOGICAL element h
          float4 hv[4];
#pragma unroll
          for (int i = 0; i < 4; i++)
            hv[i] = *(const float4*)(Hb + (((i << 4) + rg) << 6) + colh);
#pragma unroll
          for (int qq = 0; qq < 4; qq++) {
            float4 wa = *(const float4*)(w2a + qq * 256 + h);   // logical h
            float4 wb = *(const float4*)(w2b + qq * 256 + h);
#pragma unroll
            for (int i = 0; i < 4; i++) {
              acc2[i][qq]     += hv[i].x * wa.x + hv[i].y * wa.y + hv[i].z * wa.z + hv[i].w * wa.w;
              acc2[i][4 + qq] += hv[i].x * wb.x + hv[i].y * wb.y + hv[i].z * wb.z + hv[i].w * wb.w;
            }
          }
        }
      }
      __syncthreads();
    }
    // Z += acc2  (thread-exclusive slots)
#pragma unroll
    for (int i = 0; i < 4; i++) {
      int r = (i << 4) + rg;
      float4* pa = (float4*)(Z + rotZ(r, cg << 2));
      float4* pb = (float4*)(Z + rotZ(r, 64 + (cg << 2)));
      float4 za = *pa, zb = *pb;
      za.x += acc2[i][0]; za.y += acc2[i][1]; za.z += acc2[i][2]; za.w += acc2[i][3];
      zb.x += acc2[i][4]; zb.y += acc2[i][5]; zb.z += acc2[i][6]; zb.w += acc2[i][7];
      *pa = za; *pb = zb;
    }
    __syncthreads();
  }

  // ---- dist = ||rb - z||^2, argmin over 64 rows ----
  float* pd  = Hb;            // Hb free now
  int* rwin  = (int*)(Hb + 64);
  {
    const float* rb = ws + WS_RB + b * 128;
    int r = tx >> 2, qt = tx & 3;
    int dbase = qt << 5;
    int rrot = (r & 7) << 2;
    float s = 0.f;
    for (int d = 0; d < 32; d += 4) {
      int col = (dbase + d + rrot) & 127;
      float4 zv = *(const float4*)(Z + (r << 7) + col);
      float4 rv = *(const float4*)(rb + dbase + d);
      float a0 = rv.x - zv.x, a1 = rv.y - zv.y, a2 = rv.z - zv.z, a3 = rv.w - zv.w;
      s += a0 * a0 + a1 * a1 + a2 * a2 + a3 * a3;
    }
    s += __shfl_xor(s, 1);    // commutative adds: all 4 lanes bit-identical
    s += __shfl_xor(s, 2);
    if (qt == 0) pd[r] = s;
  }
  __syncthreads();
  if (tx < 64) {
    float v = pd[tx]; int idx = tx;
#pragma unroll
    for (int off = 32; off; off >>= 1) {
      float v2 = __shfl_xor(v, off);
      int   i2 = __shfl_xor(idx, off);
      if (v2 < v || (v2 == v && i2 < idx)) { v = v2; idx = i2; }
    }
    if (tx == 0) {
      ws[WS_BESTD + (b << 2) + t] = v;
      ((int*)ws)[WS_BESTI + (b << 2) + t] = k0 + idx;
      rwin[0] = idx;
    }
  }
  __syncthreads();
  if (tx < 32) {
    int rw = rwin[0];
    int col = ((tx << 2) + ((rw & 7) << 2)) & 127;
    *(float4*)(ws + WS_BESTZ + (((b << 2) + t) << 7) + (tx << 2)) =
        *(const float4*)(Z + (rw << 7) + col);
  }
}

// ---------------- per-step update: pick tile winner, advance xhat ----------------
__global__ __launch_bounds__(128) void k_update(const float* __restrict__ x,
    float* __restrict__ ws, float* __restrict__ out, int m, int last)
{
  __shared__ int tsel;
  int tx = threadIdx.x, b = blockIdx.x;
  if (tx == 0) {
    float bv = ws[WS_BESTD + (b << 2)]; int bt = 0;
    for (int q = 1; q < 4; q++) {
      float v = ws[WS_BESTD + (b << 2) + q];
      if (v < bv) { bv = v; bt = q; }     // strict <: ties -> lowest k (tile order)
    }
    tsel = bt;
    int k = ((const int*)ws)[WS_BESTI + (b << 2) + bt];
    out[OUT_CODES + b * 8 + (m + 1)] = (float)k;
  }
  __syncthreads();
  int bt = tsel;
  float z  = ws[WS_BESTZ + (((b << 2) + bt) << 7) + tx];
  float xh = ws[WS_XHAT + b * 128 + tx] + z;
  ws[WS_XHAT + b * 128 + tx] = xh;
  ws[WS_RB   + b * 128 + tx] = x[b * 128 + tx] - xh;
  out[OUT_SIDE + (m + 1) * 131072 + b * 128 + tx] = xh;
  if (last) out[b * 128 + tx] = xh;       // final xhat == side[7]
}

extern "C" void kernel_launch(void* const* d_in, const int* in_sizes, int n_in,
                              void* d_out, int out_size, void* d_ws, size_t ws_size,
                              hipStream_t stream)
{
  const float* x   = (const float*)d_in[0];
  const float* cb0 = (const float*)d_in[1];
  const float* cbs = (const float*)d_in[2];
  const float* Wc  = (const float*)d_in[3];
  const float* bc  = (const float*)d_in[4];
  const float* W1  = (const float*)d_in[5];
  const float* W2  = (const float*)d_in[6];
  float* out = (float*)d_out;
  float* ws  = (float*)d_ws;

  k_step0<<<1024, 256, 0, stream>>>(x, cb0, ws, out);
  for (int m = 0; m < 7; m++) {
    k_prep<<<1280, 128, 0, stream>>>(cbs + m * 256 * 128, Wc + m * 128 * 256,
                                     bc + m * 128, ws);
    k_step<<<4096, 256, 0, stream>>>(W1, W2, ws, m);
    k_update<<<1024, 128, 0, stream>>>(x, ws, out, m, (m == 6) ? 1 : 0);
  }
}